// Round 4
// baseline (35.613 us; speedup 1.0000x reference)
//
#include <hip/hip_runtime.h>
#include <hip/hip_fp16.h>

#define BATCH  1024
#define NVARS  2048
#define N_OUT  4096
#define NLEAF  16

__device__ __forceinline__ __half2 u2h2(unsigned u) {
    union { unsigned u; __half2 h; } c; c.u = u; return c.h;
}
__device__ __forceinline__ unsigned h22u(__half2 h) {
    union { unsigned u; __half2 h; } c; c.h = h; return c.u;
}

// ---------------- prep: convert x->fp16 AND flatten index tree ----------------
// xh: [2048][1024] fp16 (4 MB).  T[i*16+n] = int2{ byteoff=row*2048, half2(s,c) }
// leaf value = s * xh[row,col] + c   (k<2 -> s=0, c=k, row=0)
__global__ void prep_kernel(const float* __restrict__ x,
                            const int2* __restrict__ idx0,
                            const int2* __restrict__ idx1,
                            const int2* __restrict__ idx2,
                            const int2* __restrict__ idx3,
                            int2* __restrict__ T,
                            unsigned* __restrict__ xh)
{
    const int gtid = blockIdx.x * blockDim.x + threadIdx.x;   // 262144 threads

    // ---- x -> fp16, 8 floats per thread ----
    {
        const float4* x4 = (const float4*)x;
        float4 a = x4[(size_t)gtid * 2];
        float4 b = x4[(size_t)gtid * 2 + 1];
        uint4 w;
        w.x = h22u(__floats2half2_rn(a.x, a.y));
        w.y = h22u(__floats2half2_rn(a.z, a.w));
        w.z = h22u(__floats2half2_rn(b.x, b.y));
        w.w = h22u(__floats2half2_rn(b.z, b.w));
        reinterpret_cast<uint4*>(xh)[gtid] = w;
    }

    // ---- flatten (first 4096 threads) ----
    if (gtid < N_OUT) {
        const int i = gtid;
        int2 p3 = idx3[i];
        int n = 0;
        #pragma unroll
        for (int t = 0; t < 2; ++t) {
            int2 p2 = idx2[t ? p3.y : p3.x];
            #pragma unroll
            for (int u = 0; u < 2; ++u) {
                int2 p1 = idx1[u ? p2.y : p2.x];
                #pragma unroll
                for (int v = 0; v < 2; ++v) {
                    int2 p0 = idx0[v ? p1.y : p1.x];
                    #pragma unroll
                    for (int e = 0; e < 2; ++e) {
                        int k = e ? p0.y : p0.x;
                        int byteoff; float s, c;
                        if (k < 2) { byteoff = 0; s = 0.0f; c = (float)k; }
                        else {
                            byteoff = ((k - 2) >> 1) * (BATCH * 2);  // row * 2048 B
                            if (k & 1) { s = -1.0f; c = 1.0f; }
                            else       { s =  1.0f; c = 0.0f; }
                        }
                        __half2 sc = __halves2half2(__float2half(s), __float2half(c));
                        int2 ent; ent.x = byteoff; ent.y = (int)h22u(sc);
                        T[(size_t)i * NLEAF + n] = ent;
                        ++n;
                    }
                }
            }
        }
    }
}

// ---------------- main: no LDS, L2-resident gathers, full occupancy ----------------
// thread = (output o, 8-column group cg). 16 gathers of 16 B each, fp16 tree.
__global__ __launch_bounds__(256, 8) void knowledge_main(
    const char* __restrict__ xh,
    const int4* __restrict__ T4,     // T4[i*8+m] = {offA, scA, offB, scB} for pair m
    float* __restrict__ out)
{
    const int b   = blockIdx.x;          // 2048 blocks
    const int tid = threadIdx.x;
    const int o   = (b & 127) * 32 + (tid >> 3);   // output row 0..4095
    const int cg  = (b >> 7) * 8 + (tid & 7);      // col group 0..127 (8 cols each)
    const int cgoff = cg * 16;                      // byte offset within a row

    const int4* Tp = T4 + (size_t)o * 8;

    float2 accf[4];
    #pragma unroll
    for (int k = 0; k < 4; ++k) accf[k] = make_float2(0.f, 0.f);

    #pragma unroll
    for (int a3 = 0; a3 < 2; ++a3) {                  // top SumLayer
        __half2 prod2[4];
        #pragma unroll
        for (int a2 = 0; a2 < 2; ++a2) {              // ProductLayer
            __half2 sum1[4];
            #pragma unroll
            for (int a1 = 0; a1 < 2; ++a1) {          // SumLayer
                const int m = a3 * 4 + a2 * 2 + a1;
                int4 tt = Tp[m];
                uint4 A = *reinterpret_cast<const uint4*>(xh + tt.x + cgoff);
                uint4 B = *reinterpret_cast<const uint4*>(xh + tt.z + cgoff);
                __half2 scA = u2h2((unsigned)tt.y);
                __half2 scB = u2h2((unsigned)tt.w);
                __half2 sA = __half2half2(__low2half(scA));
                __half2 cA = __half2half2(__high2half(scA));
                __half2 sB = __half2half2(__low2half(scB));
                __half2 cB = __half2half2(__high2half(scB));
                unsigned aw[4] = {A.x, A.y, A.z, A.w};
                unsigned bw[4] = {B.x, B.y, B.z, B.w};
                #pragma unroll
                for (int k = 0; k < 4; ++k) {
                    __half2 va = __hfma2(u2h2(aw[k]), sA, cA);
                    __half2 vb = __hfma2(u2h2(bw[k]), sB, cB);
                    __half2 p  = __hmul2(va, vb);              // leaf product
                    if (a1 == 0) sum1[k] = p;
                    else         sum1[k] = __hadd2(sum1[k], p); // SumLayer
                }
            }
            #pragma unroll
            for (int k = 0; k < 4; ++k) {
                if (a2 == 0) prod2[k] = sum1[k];
                else         prod2[k] = __hmul2(prod2[k], sum1[k]); // ProductLayer
            }
        }
        #pragma unroll
        for (int k = 0; k < 4; ++k) {                 // top sum in f32
            float2 pf = __half22float2(prod2[k]);
            accf[k].x += pf.x; accf[k].y += pf.y;
        }
    }

    float* dst = out + (size_t)o * BATCH + cg * 8;
    reinterpret_cast<float4*>(dst)[0] = make_float4(accf[0].x, accf[0].y, accf[1].x, accf[1].y);
    reinterpret_cast<float4*>(dst)[1] = make_float4(accf[2].x, accf[2].y, accf[3].x, accf[3].y);
}

// ---------------- fallback (round-1 kernel) if ws too small ----------------
__device__ __forceinline__ float Hval(int k, const float* __restrict__ x, int b) {
    if (k < 2) return (float)k;
    float v = x[((k - 2) >> 1) * BATCH + b];
    return (k & 1) ? 1.0f - v : v;
}

__global__ __launch_bounds__(256) void knowledge_fused_kernel(
    const float* __restrict__ x,
    const int2* __restrict__ idx0,
    const int2* __restrict__ idx1,
    const int2* __restrict__ idx2,
    const int2* __restrict__ idx3,
    float* __restrict__ out)
{
    const int i = blockIdx.x;
    const int b = blockIdx.y * blockDim.x + threadIdx.x;
    const int2 p3 = idx3[i];
    float acc3 = 0.0f;
    #pragma unroll
    for (int t = 0; t < 2; ++t) {
        const int2 p2 = idx2[t ? p3.y : p3.x];
        float prod2 = 1.0f;
        #pragma unroll
        for (int u = 0; u < 2; ++u) {
            const int2 p1 = idx1[u ? p2.y : p2.x];
            float sum1 = 0.0f;
            #pragma unroll
            for (int v = 0; v < 2; ++v) {
                const int2 p0 = idx0[v ? p1.y : p1.x];
                sum1 += Hval(p0.x, x, b) * Hval(p0.y, x, b);
            }
            prod2 *= sum1;
        }
        acc3 += prod2;
    }
    out[(size_t)i * BATCH + b] = acc3;
}

extern "C" void kernel_launch(void* const* d_in, const int* in_sizes, int n_in,
                              void* d_out, int out_size, void* d_ws, size_t ws_size,
                              hipStream_t stream) {
    const float* x    = (const float*)d_in[0];
    const int2*  idx0 = (const int2*)d_in[1];
    const int2*  idx1 = (const int2*)d_in[2];
    const int2*  idx2 = (const int2*)d_in[3];
    const int2*  idx3 = (const int2*)d_in[4];
    float* out = (float*)d_out;

    const size_t t_bytes  = (size_t)N_OUT * NLEAF * sizeof(int2);        // 512 KB
    const size_t xh_bytes = (size_t)NVARS * BATCH * sizeof(__half);      // 4 MB
    if (ws_size >= t_bytes + xh_bytes) {
        int2*     T  = (int2*)d_ws;
        unsigned* xh = (unsigned*)((char*)d_ws + t_bytes);
        prep_kernel<<<(NVARS * BATCH / 8) / 256, 256, 0, stream>>>(
            x, idx0, idx1, idx2, idx3, T, xh);
        knowledge_main<<<2048, 256, 0, stream>>>(
            (const char*)xh, (const int4*)T, out);
    } else {
        dim3 grid(N_OUT, BATCH / 256);
        knowledge_fused_kernel<<<grid, 256, 0, stream>>>(x, idx0, idx1, idx2, idx3, out);
    }
}

// Round 5
// 20.729 us; speedup vs baseline: 1.7180x; 1.7180x over previous
//
#include <hip/hip_runtime.h>
#include <hip/hip_fp16.h>

#define BATCH  1024
#define NVARS  2048
#define N_OUT  4096

typedef float f32x4 __attribute__((ext_vector_type(4)));

__device__ __forceinline__ __half2 u2h2(unsigned u) {
    union { unsigned u; __half2 h; } c; c.u = u; return c.h;
}
__device__ __forceinline__ unsigned h22u(__half2 h) {
    union { unsigned u; __half2 h; } c; c.h = h; return c.u;
}

// ---------------- prep: x->fp16 AND flatten index tree (packed) ----------------
// xh: [2048][1024] fp16 (4 MB).
// T[i*8+m] = leafA | leafB<<16, leaf = sel<<11 | row (13 bits).
// sel: 0 -> 0, 1 -> 1, 2 -> x[row], 3 -> 1-x[row]
__global__ void prep_kernel(const float* __restrict__ x,
                            const int2* __restrict__ idx0,
                            const int2* __restrict__ idx1,
                            const int2* __restrict__ idx2,
                            const int2* __restrict__ idx3,
                            unsigned* __restrict__ T,
                            unsigned* __restrict__ xh)
{
    const int gtid = blockIdx.x * blockDim.x + threadIdx.x;   // 262144 threads

    // ---- x -> fp16, 8 floats per thread ----
    {
        const float4* x4 = (const float4*)x;
        float4 a = x4[(size_t)gtid * 2];
        float4 b = x4[(size_t)gtid * 2 + 1];
        uint4 w;
        w.x = h22u(__floats2half2_rn(a.x, a.y));
        w.y = h22u(__floats2half2_rn(a.z, a.w));
        w.z = h22u(__floats2half2_rn(b.x, b.y));
        w.w = h22u(__floats2half2_rn(b.z, b.w));
        reinterpret_cast<uint4*>(xh)[gtid] = w;
    }

    // ---- flatten (first 4096 threads) ----
    if (gtid < N_OUT) {
        const int i = gtid;
        int2 p3 = idx3[i];
        int n = 0;
        #pragma unroll
        for (int t = 0; t < 2; ++t) {
            int2 p2 = idx2[t ? p3.y : p3.x];
            #pragma unroll
            for (int u = 0; u < 2; ++u) {
                int2 p1 = idx1[u ? p2.y : p2.x];
                #pragma unroll
                for (int v = 0; v < 2; ++v) {
                    int2 p0 = idx0[v ? p1.y : p1.x];
                    unsigned w = 0;
                    #pragma unroll
                    for (int e = 0; e < 2; ++e) {
                        int k = e ? p0.y : p0.x;
                        unsigned code;
                        if (k < 2) code = (unsigned)k << 11;                       // sel=k,row=0
                        else       code = ((2u + (k & 1)) << 11) | ((unsigned)(k - 2) >> 1);
                        w |= code << (16 * e);
                    }
                    T[(size_t)i * 8 + n] = w;
                    ++n;
                }
            }
        }
    }
}

__device__ __forceinline__ void sel2sc(unsigned sel, unsigned& s, unsigned& c) {
    // half2 broadcast constants: 1.0h2 = 0x3C003C00, -1.0h2 = 0xBC00BC00
    c = (sel & 1u) ? 0x3C003C00u : 0u;
    s = (sel == 2u) ? 0x3C003C00u : (sel == 3u) ? 0xBC00BC00u : 0u;
}

// ---------------- main: no LDS, per-XCD column slice, NT stores ----------------
// XCD = bx%8; cg octet = bx&15 -> each XCD touches only 2 column-octets of xh
// (2048 rows x 2x128 B = 512 KB working set, L2-resident).
__global__ __launch_bounds__(256) void knowledge_main(
    const char* __restrict__ xh,
    const uint4* __restrict__ T4,     // 2 x uint4 per output (8 packed pairs)
    float* __restrict__ out)
{
    const int bx  = blockIdx.x;          // 2048 blocks
    const int tid = threadIdx.x;
    const int octet = bx & 15;                      // col-group octet 0..15
    const int o     = (bx >> 4) * 32 + (tid >> 3);  // output row 0..4095
    const int cg    = octet * 8 + (tid & 7);        // col group 0..127 (8 cols)
    const char* base = xh + cg * 16;                // this thread's column window

    uint4 t0 = T4[(size_t)o * 2];
    uint4 t1 = T4[(size_t)o * 2 + 1];
    const unsigned tw[8] = {t0.x, t0.y, t0.z, t0.w, t1.x, t1.y, t1.z, t1.w};

    // issue all 16 gathers up front (max MLP)
    uint4 Aw[8], Bw[8];
    #pragma unroll
    for (int m = 0; m < 8; ++m) {
        unsigned w = tw[m];
        Aw[m] = *reinterpret_cast<const uint4*>(base + ((w & 0x7FFu) << 11));
        Bw[m] = *reinterpret_cast<const uint4*>(base + (((w >> 16) & 0x7FFu) << 11));
    }

    float2 accf[4];
    #pragma unroll
    for (int k = 0; k < 4; ++k) accf[k] = make_float2(0.f, 0.f);

    #pragma unroll
    for (int a3 = 0; a3 < 2; ++a3) {                  // top SumLayer
        __half2 prod2[4];
        #pragma unroll
        for (int a2 = 0; a2 < 2; ++a2) {              // ProductLayer
            __half2 sum1[4];
            #pragma unroll
            for (int a1 = 0; a1 < 2; ++a1) {          // SumLayer
                const int m = a3 * 4 + a2 * 2 + a1;
                unsigned w = tw[m];
                unsigned sa, ca, sb, cb;
                sel2sc((w >> 11) & 3u, sa, ca);
                sel2sc((w >> 27) & 3u, sb, cb);
                __half2 sA = u2h2(sa), cA = u2h2(ca);
                __half2 sB = u2h2(sb), cB = u2h2(cb);
                const unsigned aw[4] = {Aw[m].x, Aw[m].y, Aw[m].z, Aw[m].w};
                const unsigned bw[4] = {Bw[m].x, Bw[m].y, Bw[m].z, Bw[m].w};
                #pragma unroll
                for (int k = 0; k < 4; ++k) {
                    __half2 va = __hfma2(u2h2(aw[k]), sA, cA);
                    __half2 vb = __hfma2(u2h2(bw[k]), sB, cB);
                    __half2 p  = __hmul2(va, vb);               // leaf product
                    if (a1 == 0) sum1[k] = p;
                    else         sum1[k] = __hadd2(sum1[k], p); // SumLayer
                }
            }
            #pragma unroll
            for (int k = 0; k < 4; ++k) {
                if (a2 == 0) prod2[k] = sum1[k];
                else         prod2[k] = __hmul2(prod2[k], sum1[k]);  // ProductLayer
            }
        }
        #pragma unroll
        for (int k = 0; k < 4; ++k) {                 // top sum in f32
            float2 pf = __half22float2(prod2[k]);
            accf[k].x += pf.x; accf[k].y += pf.y;
        }
    }

    float* dst = out + (size_t)o * BATCH + cg * 8;
    f32x4 o0 = {accf[0].x, accf[0].y, accf[1].x, accf[1].y};
    f32x4 o1 = {accf[2].x, accf[2].y, accf[3].x, accf[3].y};
    __builtin_nontemporal_store(o0, reinterpret_cast<f32x4*>(dst));
    __builtin_nontemporal_store(o1, reinterpret_cast<f32x4*>(dst) + 1);
}

// ---------------- fallback (round-1 kernel) if ws too small ----------------
__device__ __forceinline__ float Hval(int k, const float* __restrict__ x, int b) {
    if (k < 2) return (float)k;
    float v = x[((k - 2) >> 1) * BATCH + b];
    return (k & 1) ? 1.0f - v : v;
}

__global__ __launch_bounds__(256) void knowledge_fused_kernel(
    const float* __restrict__ x,
    const int2* __restrict__ idx0,
    const int2* __restrict__ idx1,
    const int2* __restrict__ idx2,
    const int2* __restrict__ idx3,
    float* __restrict__ out)
{
    const int i = blockIdx.x;
    const int b = blockIdx.y * blockDim.x + threadIdx.x;
    const int2 p3 = idx3[i];
    float acc3 = 0.0f;
    #pragma unroll
    for (int t = 0; t < 2; ++t) {
        const int2 p2 = idx2[t ? p3.y : p3.x];
        float prod2 = 1.0f;
        #pragma unroll
        for (int u = 0; u < 2; ++u) {
            const int2 p1 = idx1[u ? p2.y : p2.x];
            float sum1 = 0.0f;
            #pragma unroll
            for (int v = 0; v < 2; ++v) {
                const int2 p0 = idx0[v ? p1.y : p1.x];
                sum1 += Hval(p0.x, x, b) * Hval(p0.y, x, b);
            }
            prod2 *= sum1;
        }
        acc3 += prod2;
    }
    out[(size_t)i * BATCH + b] = acc3;
}

extern "C" void kernel_launch(void* const* d_in, const int* in_sizes, int n_in,
                              void* d_out, int out_size, void* d_ws, size_t ws_size,
                              hipStream_t stream) {
    const float* x    = (const float*)d_in[0];
    const int2*  idx0 = (const int2*)d_in[1];
    const int2*  idx1 = (const int2*)d_in[2];
    const int2*  idx2 = (const int2*)d_in[3];
    const int2*  idx3 = (const int2*)d_in[4];
    float* out = (float*)d_out;

    const size_t t_bytes  = (size_t)N_OUT * 8 * sizeof(unsigned);        // 128 KB
    const size_t xh_bytes = (size_t)NVARS * BATCH * sizeof(__half);      // 4 MB
    if (ws_size >= t_bytes + xh_bytes) {
        unsigned* T  = (unsigned*)d_ws;
        unsigned* xh = (unsigned*)((char*)d_ws + t_bytes);
        prep_kernel<<<(NVARS * BATCH / 8) / 256, 256, 0, stream>>>(
            x, idx0, idx1, idx2, idx3, T, xh);
        knowledge_main<<<2048, 256, 0, stream>>>(
            (const char*)xh, (const uint4*)T, out);
    } else {
        dim3 grid(N_OUT, BATCH / 256);
        knowledge_fused_kernel<<<grid, 256, 0, stream>>>(x, idx0, idx1, idx2, idx3, out);
    }
}